// Round 6
// baseline (255.919 us; speedup 1.0000x reference)
//
#include <hip/hip_runtime.h>

typedef unsigned short u16;
typedef unsigned int u32;
typedef __bf16 bf16x8 __attribute__((ext_vector_type(8)));
typedef float f32x4 __attribute__((ext_vector_type(4)));
typedef float f32x16 __attribute__((ext_vector_type(16)));

extern "C" __device__ float __ocml_native_exp2_f32(float);

// workspace offsets in u16 elements
#define WT_HI_E  ((size_t)0)             // 3 x 1M
#define WT_LO_E  ((size_t)3 << 20)
#define X_HI_E   ((size_t)6 << 20)       // 4M each below
#define X_LO_E   ((size_t)10 << 20)
#define Q_HI_E   ((size_t)14 << 20)
#define Q_LO_E   ((size_t)18 << 20)
#define K_HI_E   ((size_t)22 << 20)      // [hb][s][64] d-chunk-XOR-swizzled
#define K_LO_E   ((size_t)26 << 20)
#define V_HI_E   ((size_t)30 << 20)      // V^T [hb][d][2048], s-chunk-XOR-swizzled per 64-key block
// attention partials reuse the dead WT/X region after k_proj:
#define O1_E     ((size_t)0)             // split-1 partial O, 8M u16 (fp32 32*2048*64)
#define ML_E     ((size_t)9 << 20)       // m0,l0,m1,l1 each 65536 fp32

__device__ __forceinline__ u16 bf16_rne(float x) {
  u32 u = __float_as_uint(x);
  u32 r = (u + 0x7fffu + ((u >> 16) & 1u)) >> 16;
  return (u16)r;
}
__device__ __forceinline__ float bf16_f(u16 h) {
  return __uint_as_float(((u32)h) << 16);
}

__device__ __forceinline__ void gload16(const u16* g, u16* l) {
  __builtin_amdgcn_global_load_lds(
      (const __attribute__((address_space(1))) void*)g,
      (__attribute__((address_space(3))) void*)l, 16, 0, 0);
}

// ---------------- X split: fp32 -> bf16 hi/lo ----------------
__global__ __launch_bounds__(256) void k_xsplit(const float* __restrict__ X,
                                                u16* __restrict__ ws) {
  u16* xh = ws + X_HI_E;
  u16* xl = ws + X_LO_E;
  size_t i = ((size_t)blockIdx.x * 256 + threadIdx.x) * 8;
  float4 a = *(const float4*)(X + i);
  float4 b = *(const float4*)(X + i + 4);
  float v[8] = {a.x, a.y, a.z, a.w, b.x, b.y, b.z, b.w};
  u32 Hh[4], Ll[4];
#pragma unroll
  for (int j = 0; j < 4; j++) {
    u16 h0 = bf16_rne(v[2 * j]);
    u16 l0 = bf16_rne(v[2 * j] - bf16_f(h0));
    u16 h1 = bf16_rne(v[2 * j + 1]);
    u16 l1 = bf16_rne(v[2 * j + 1] - bf16_f(h1));
    Hh[j] = (u32)h0 | ((u32)h1 << 16);
    Ll[j] = (u32)l0 | ((u32)l1 << 16);
  }
  *(uint4*)(xh + i) = make_uint4(Hh[0], Hh[1], Hh[2], Hh[3]);
  *(uint4*)(xl + i) = make_uint4(Ll[0], Ll[1], Ll[2], Ll[3]);
}

// ---------------- W transpose + split: W[k][n] -> Wt_hi/lo[n][k] ----------------
__global__ __launch_bounds__(256) void k_wsplit(const float* __restrict__ w0,
                                                const float* __restrict__ w1,
                                                const float* __restrict__ w2,
                                                u16* __restrict__ ws) {
  int z = blockIdx.z;
  const float* W = (z == 0) ? w0 : ((z == 1) ? w1 : w2);
  u16* th = ws + WT_HI_E + (size_t)z * (1u << 20);
  u16* tl = ws + WT_LO_E + (size_t)z * (1u << 20);
  __shared__ float tile[32][33];
  int bx = blockIdx.x * 32, by = blockIdx.y * 32;
  int tx = threadIdx.x & 31, ty = threadIdx.x >> 5;  // 32 x 8
#pragma unroll
  for (int i = 0; i < 4; i++) {
    int r = ty + i * 8;
    tile[r][tx] = W[(size_t)(by + r) * 1024 + bx + tx];
  }
  __syncthreads();
#pragma unroll
  for (int i = 0; i < 4; i++) {
    int r = ty + i * 8;
    float v = tile[tx][r];  // = W[by+tx][bx+r]
    int n = bx + r, k = by + tx;
    u16 h = bf16_rne(v);
    u16 l = bf16_rne(v - bf16_f(h));
    th[(size_t)n * 1024 + k] = h;
    tl[(size_t)n * 1024 + k] = l;
  }
}

// ---------------- projections: Y = X @ W, compensated bf16 MFMA ----------------
// z=0 -> Q*(0.125*log2e) (hi+lo, linear), z=1 -> K (hi+lo, d-chunk swizzled),
// z=2 -> V (hi only, stored transposed, s-chunk swizzled per 64-key block).
__global__ __launch_bounds__(256) void k_proj(u16* __restrict__ ws) {
  int z = blockIdx.z;
  const u16* Xh = ws + X_HI_E;
  const u16* Xl = ws + X_LO_E;
  const u16* Wh = ws + WT_HI_E + (size_t)z * (1u << 20);
  const u16* Wl = ws + WT_LO_E + (size_t)z * (1u << 20);
  u16* dsth = ws + ((z == 0) ? Q_HI_E : ((z == 1) ? K_HI_E : V_HI_E));
  u16* dstl = (z == 0) ? (ws + Q_LO_E) : ((z == 1) ? (ws + K_LO_E) : (u16*)0);

  __shared__ u16 sXh[4096], sXl[4096], sWh[4096], sWl[4096];
  int M0 = blockIdx.y * 128, N0 = blockIdx.x * 128;
  int tid = threadIdx.x, lane = tid & 63, w = tid >> 6;
  int quad = lane >> 4, l16 = lane & 15;
  int mb = (w & 1) * 64, nb = (w >> 1) * 64;

  const f32x4 z4 = {0.f, 0.f, 0.f, 0.f};
  f32x4 acc[4][4];
#pragma unroll
  for (int i = 0; i < 4; i++)
#pragma unroll
    for (int j = 0; j < 4; j++) acc[i][j] = z4;

  for (int kk = 0; kk < 1024; kk += 32) {
    __syncthreads();
#pragma unroll
    for (int c2 = 0; c2 < 2; c2++) {
      int cb = c2 * 256 + w * 64;
      int c = cb + lane;
      int row = c >> 2, q8 = c & 3;
      size_t gx = (size_t)(M0 + row) * 1024 + kk + q8 * 8;
      size_t gw = (size_t)(N0 + row) * 1024 + kk + q8 * 8;
      gload16(Xh + gx, sXh + (size_t)cb * 8);
      gload16(Wh + gw, sWh + (size_t)cb * 8);
      if (z != 2) {
        gload16(Xl + gx, sXl + (size_t)cb * 8);
        gload16(Wl + gw, sWl + (size_t)cb * 8);
      }
    }
    __syncthreads();
    bf16x8 ah[4], bh[4];
#pragma unroll
    for (int i = 0; i < 4; i++) {
      ah[i] = *(const bf16x8*)&sXh[(mb + i * 16 + l16) * 32 + quad * 8];
      bh[i] = *(const bf16x8*)&sWh[(nb + i * 16 + l16) * 32 + quad * 8];
    }
    if (z != 2) {
      bf16x8 al[4], bl[4];
#pragma unroll
      for (int i = 0; i < 4; i++) {
        al[i] = *(const bf16x8*)&sXl[(mb + i * 16 + l16) * 32 + quad * 8];
        bl[i] = *(const bf16x8*)&sWl[(nb + i * 16 + l16) * 32 + quad * 8];
      }
#pragma unroll
      for (int i = 0; i < 4; i++)
#pragma unroll
        for (int j = 0; j < 4; j++) {
          f32x4 c0 = acc[i][j];
          c0 = __builtin_amdgcn_mfma_f32_16x16x32_bf16(ah[i], bh[j], c0, 0, 0, 0);
          c0 = __builtin_amdgcn_mfma_f32_16x16x32_bf16(ah[i], bl[j], c0, 0, 0, 0);
          c0 = __builtin_amdgcn_mfma_f32_16x16x32_bf16(al[i], bh[j], c0, 0, 0, 0);
          acc[i][j] = c0;
        }
    } else {
#pragma unroll
      for (int i = 0; i < 4; i++)
#pragma unroll
        for (int j = 0; j < 4; j++)
          acc[i][j] = __builtin_amdgcn_mfma_f32_16x16x32_bf16(ah[i], bh[j], acc[i][j], 0, 0, 0);
    }
  }

  if (z == 2) {
    // V^T store with s-chunk swizzle: within each 64-key block, 8-key chunk
    // c -> c ^ (d&7). uint2 (4 keys, s%8 in {0,4}) stays inside one chunk.
#pragma unroll
    for (int i = 0; i < 4; i++)
#pragma unroll
      for (int j = 0; j < 4; j++) {
        int mg = M0 + mb + i * 16 + quad * 4;
        int ng = N0 + nb + j * 16 + l16;
        int b = mg >> 11, s = mg & 2047;
        int hh = ng >> 6, d = ng & 63;
        int cp = ((s >> 3) & 7) ^ (d & 7);
        int ssw = (s & ~63) | (cp << 3) | (s & 7);
        u16 p0 = bf16_rne(acc[i][j][0]);
        u16 p1 = bf16_rne(acc[i][j][1]);
        u16 p2 = bf16_rne(acc[i][j][2]);
        u16 p3 = bf16_rne(acc[i][j][3]);
        *(uint2*)&dsth[((size_t)(hh * 2 + b) * 64 + d) * 2048 + ssw] =
            make_uint2((u32)p0 | ((u32)p1 << 16), (u32)p2 | ((u32)p3 << 16));
      }
  } else {
    // Q scale: 1/sqrt(dh) * log2(e) -> scores land in log2 domain (exp2 softmax)
    float qscale = (z == 0) ? (0.125f * 1.4426950408889634f) : 1.0f;
#pragma unroll
    for (int i = 0; i < 4; i++)
#pragma unroll
      for (int j = 0; j < 4; j++)
#pragma unroll
        for (int r = 0; r < 4; r++) {
          int mg = M0 + mb + i * 16 + quad * 4 + r;
          int ng = N0 + nb + j * 16 + l16;
          int b = mg >> 11, s = mg & 2047;
          int hh = ng >> 6, d = ng & 63;
          int d2 = d;
          if (z == 1) d2 = ((((d >> 3) ^ (s & 7)) & 7) << 3) | (d & 7);  // K swizzle
          size_t idx = ((size_t)(hh * 2 + b) * 2048 + s) * 64 + d2;
          float y = acc[i][j][r] * qscale;
          u16 h = bf16_rne(y);
          dsth[idx] = h;
          dstl[idx] = bf16_rne(y - bf16_f(h));
        }
  }
}

// ---------------- flash attention: 32x32 MFMA, kt-split x2, 16 waves/CU ----------------
// grid 1024 = 32 hb x 16 qb x 2 kt-splits; 4 waves/block, 32 queries/wave.
// Single-buffered 24 KB K/V staging (4 blocks/CU even) -> occupancy doubles
// vs round-5's 2-block dbuf. S^T = K·Q^T in-register softmax (per-lane stats),
// P^T assembled via shfl_xor(32). Writes UNNORMALIZED partial O + (m,l).
__global__ __launch_bounds__(256, 4) void k_attn(u16* __restrict__ ws,
                                                 float* __restrict__ out) {
  const u16* Qh = ws + Q_HI_E;
  const u16* Ql = ws + Q_LO_E;
  const u16* Kh = ws + K_HI_E;
  const u16* Kl = ws + K_LO_E;
  const u16* Vt = ws + V_HI_E;
  float* o1 = (float*)(ws + O1_E);
  float* ml = (float*)(ws + ML_E);

  __shared__ u16 sKh[64][64], sKl[64][64], sVt[64][64];  // 24 KB single-buffer

  int id = blockIdx.x;
  int hb = id & 31;  // id&7 = XCD: 4 hbs' K/V (~3 MB) resident per XCD L2
  int rem = id >> 5;
  int qb = rem >> 1, split = rem & 1;
  int kt0 = split * 1024;

  int tid = threadIdx.x, w = tid >> 6, lane = tid & 63;
  int l31 = lane & 31, h = lane >> 5;
  size_t base = (size_t)hb * (2048 * 64);
  int qw0 = qb * 128 + w * 32;

  int srow = lane >> 3, sch = lane & 7;  // staging: 8 rows x 128B per wave-instr

  // Q B-operand frags (n = query = l31, k-step ks: d = ks*16 + h*8), linear layout
  bf16x8 qh[4], ql[4];
#pragma unroll
  for (int ks = 0; ks < 4; ks++) {
    size_t off = base + (size_t)(qw0 + l31) * 64 + ks * 16 + h * 8;
    qh[ks] = *(const bf16x8*)(Qh + off);
    ql[ks] = *(const bf16x8*)(Ql + off);
  }

  f32x16 o[2];
#pragma unroll
  for (int i = 0; i < 16; i++) { o[0][i] = 0.f; o[1][i] = 0.f; }
  float mr = -1e30f, lr = 0.f;

  // A-operand read from a swizzled tile: row = mt*32 + l31, chunk = (ks*2+h)^(row&7)
  auto rdA = [&](const u16 t[64][64], int mt, int ks) -> bf16x8 {
    int ch = ((ks * 2 + h) ^ (l31 & 7)) * 8;
    return *(const bf16x8*)&t[mt * 32 + l31][ch];
  };

  for (int it = 0; it < 16; it++) {
    int kt = kt0 + it * 64;
    __syncthreads();  // previous iteration's reads complete -> safe to overwrite
#pragma unroll
    for (int b2 = 0; b2 < 2; b2++) {
      int rr = w * 16 + b2 * 8;
      size_t kg = base + (size_t)(kt + rr + srow) * 64 + sch * 8;
      gload16(Kh + kg, &sKh[rr][0]);
      gload16(Kl + kg, &sKl[rr][0]);
      size_t vg = base + (size_t)(rr + srow) * 2048 + kt + sch * 8;
      gload16(Vt + vg, &sVt[rr][0]);
    }
    __syncthreads();  // DMA drained (L2-resident, ~200-400 cyc, hidden by 4 blocks/CU)

    // S^T = K·Q^T (compensated): lane holds query l31, its h-half of 64 keys
    f32x16 sc[2];
#pragma unroll
    for (int i = 0; i < 16; i++) { sc[0][i] = 0.f; sc[1][i] = 0.f; }
#pragma unroll
    for (int ks = 0; ks < 4; ks++)
#pragma unroll
      for (int mt = 0; mt < 2; mt++) {
        bf16x8 kh = rdA(sKh, mt, ks);
        bf16x8 kl = rdA(sKl, mt, ks);
        sc[mt] = __builtin_amdgcn_mfma_f32_32x32x16_bf16(kh, qh[ks], sc[mt], 0, 0, 0);
        sc[mt] = __builtin_amdgcn_mfma_f32_32x32x16_bf16(kh, ql[ks], sc[mt], 0, 0, 0);
        sc[mt] = __builtin_amdgcn_mfma_f32_32x32x16_bf16(kl, qh[ks], sc[mt], 0, 0, 0);
      }

    // online softmax (log2 domain): per-lane scalar stats, 1 shfl max + 1 shfl sum
    float mx = sc[0][0];
#pragma unroll
    for (int i = 0; i < 16; i++) {
      mx = fmaxf(mx, sc[0][i]);
      mx = fmaxf(mx, sc[1][i]);
    }
    mx = fmaxf(mx, __shfl_xor(mx, 32));
    float mnew = fmaxf(mr, mx);
    float alpha = __ocml_native_exp2_f32(mr - mnew);
    mr = mnew;
    float rs = 0.f;
    u32 pk[2][8];
#pragma unroll
    for (int t = 0; t < 2; t++)
#pragma unroll
      for (int i = 0; i < 8; i++) {
        float p0 = __ocml_native_exp2_f32(sc[t][2 * i] - mnew);
        float p1 = __ocml_native_exp2_f32(sc[t][2 * i + 1] - mnew);
        rs += p0 + p1;
        u32 a = __float_as_uint(p0) + 0x8000u;
        u32 b = __float_as_uint(p1) + 0x8000u;
        pk[t][i] = __builtin_amdgcn_perm(b, a, 0x07060302u);  // [hi16(a)|hi16(b)]
      }
    rs += __shfl_xor(rs, 32);
    lr = lr * alpha + rs;
#pragma unroll
    for (int i = 0; i < 16; i++) {
      o[0][i] *= alpha;
      o[1][i] *= alpha;
    }

    // O^T += V^T · P^T : B-frag (k=key, n=query) assembled from S^T regs via xor-32
#pragma unroll
    for (int ks = 0; ks < 4; ks++) {
      int t = ks >> 1, c = ks & 1;
      u32 b0 = pk[t][c * 4 + 0], b1 = pk[t][c * 4 + 1];
      u32 b2 = pk[t][c * 4 + 2], b3 = pk[t][c * 4 + 3];
      u32 rA = (u32)__shfl_xor((int)(h ? b0 : b2), 32);
      u32 rB = (u32)__shfl_xor((int)(h ? b1 : b3), 32);
      uint4 fb = h ? make_uint4(rA, rB, b2, b3) : make_uint4(b0, b1, rA, rB);
      bf16x8 pfrag = *(bf16x8*)&fb;
#pragma unroll
      for (int mt = 0; mt < 2; mt++) {
        bf16x8 vb = rdA(sVt, mt, ks);
        o[mt] = __builtin_amdgcn_mfma_f32_32x32x16_bf16(vb, pfrag, o[mt], 0, 0, 0);
      }
    }
  }

  // epilogue: UNNORMALIZED partial O^T + per-query (m,l); combine merges splits
  float* op = split ? o1 : out;
  float* mlp = ml + (size_t)split * 131072;
  size_t g = (size_t)hb * 2048 + qw0 + l31;
  if (h == 0) {
    mlp[g] = mr;
    mlp[65536 + g] = lr;
  }
#pragma unroll
  for (int mt = 0; mt < 2; mt++)
#pragma unroll
    for (int g2 = 0; g2 < 4; g2++) {
      int d0 = mt * 32 + g2 * 8 + 4 * h;
      float4 v = make_float4(o[mt][g2 * 4 + 0], o[mt][g2 * 4 + 1],
                             o[mt][g2 * 4 + 2], o[mt][g2 * 4 + 3]);
      *(float4*)(op + g * 64 + d0) = v;
    }
}

// ---------------- combine the 2 kt-splits ----------------
__global__ __launch_bounds__(256) void k_combine(const u16* __restrict__ ws,
                                                 float* __restrict__ out) {
  const float* o1 = (const float*)(ws + O1_E);
  const float* ml = (const float*)(ws + ML_E);
  size_t idx = (size_t)blockIdx.x * 256 + threadIdx.x;  // float4 index, 1M total
  size_t g = idx >> 4;                                  // row id (64 f32 = 16 float4)
  float m0 = ml[g], l0 = ml[65536 + g];
  float m1 = ml[131072 + g], l1 = ml[196608 + g];
  float M = fmaxf(m0, m1);
  float w0 = __ocml_native_exp2_f32(m0 - M), w1 = __ocml_native_exp2_f32(m1 - M);
  float inv = 1.f / (l0 * w0 + l1 * w1);
  float4 a = ((const float4*)out)[idx];
  float4 b = ((const float4*)o1)[idx];
  float4 r;
  r.x = (a.x * w0 + b.x * w1) * inv;
  r.y = (a.y * w0 + b.y * w1) * inv;
  r.z = (a.z * w0 + b.z * w1) * inv;
  r.w = (a.w * w0 + b.w * w1) * inv;
  ((float4*)out)[idx] = r;
}

extern "C" void kernel_launch(void* const* d_in, const int* in_sizes, int n_in,
                              void* d_out, int out_size, void* d_ws, size_t ws_size,
                              hipStream_t stream) {
  const float* X = (const float*)d_in[0];
  const float* Wq = (const float*)d_in[1];
  const float* Wk = (const float*)d_in[2];
  const float* Wv = (const float*)d_in[3];
  u16* ws = (u16*)d_ws;
  float* out = (float*)d_out;

  k_xsplit<<<dim3(2048), dim3(256), 0, stream>>>(X, ws);
  k_wsplit<<<dim3(32, 32, 3), dim3(256), 0, stream>>>(Wq, Wk, Wv, ws);
  k_proj<<<dim3(8, 32, 3), dim3(256), 0, stream>>>(ws);
  k_attn<<<dim3(1024), dim3(256), 0, stream>>>(ws, out);
  k_combine<<<dim3(4096), dim3(256), 0, stream>>>(ws, out);
}

// Round 7
// 236.335 us; speedup vs baseline: 1.0829x; 1.0829x over previous
//
#include <hip/hip_runtime.h>

typedef unsigned short u16;
typedef unsigned int u32;
typedef __bf16 bf16x8 __attribute__((ext_vector_type(8)));
typedef float f32x4 __attribute__((ext_vector_type(4)));
typedef float f32x16 __attribute__((ext_vector_type(16)));

extern "C" __device__ float __ocml_native_exp2_f32(float);

// workspace offsets in u16 elements
#define WT_HI_E  ((size_t)0)             // 3 x 1M
#define WT_LO_E  ((size_t)3 << 20)
#define X_HI_E   ((size_t)6 << 20)       // 4M each below
#define X_LO_E   ((size_t)10 << 20)
#define Q_HI_E   ((size_t)14 << 20)
#define Q_LO_E   ((size_t)18 << 20)
#define K_HI_E   ((size_t)22 << 20)      // [hb][s][64] d-chunk-XOR-swizzled
#define K_LO_E   ((size_t)26 << 20)
#define V_HI_E   ((size_t)30 << 20)      // V^T [hb][d][2048], s-chunk-XOR-swizzled per 64-key block

__device__ __forceinline__ u16 bf16_rne(float x) {
  u32 u = __float_as_uint(x);
  u32 r = (u + 0x7fffu + ((u >> 16) & 1u)) >> 16;
  return (u16)r;
}
__device__ __forceinline__ float bf16_f(u16 h) {
  return __uint_as_float(((u32)h) << 16);
}

__device__ __forceinline__ void gload16(const u16* g, u16* l) {
  __builtin_amdgcn_global_load_lds(
      (const __attribute__((address_space(1))) void*)g,
      (__attribute__((address_space(3))) void*)l, 16, 0, 0);
}

// ---------------- fused input prep: X split + W transpose/split ----------------
// blocks [0,2048): X fp32 -> bf16 hi/lo.  blocks [2048,5120): W^T hi/lo.
__global__ __launch_bounds__(256) void k_split(const float* __restrict__ X,
                                               const float* __restrict__ w0,
                                               const float* __restrict__ w1,
                                               const float* __restrict__ w2,
                                               u16* __restrict__ ws) {
  int bid = blockIdx.x;
  if (bid < 2048) {
    u16* xh = ws + X_HI_E;
    u16* xl = ws + X_LO_E;
    size_t i = ((size_t)bid * 256 + threadIdx.x) * 8;
    float4 a = *(const float4*)(X + i);
    float4 b = *(const float4*)(X + i + 4);
    float v[8] = {a.x, a.y, a.z, a.w, b.x, b.y, b.z, b.w};
    u32 Hh[4], Ll[4];
#pragma unroll
    for (int j = 0; j < 4; j++) {
      u16 h0 = bf16_rne(v[2 * j]);
      u16 l0 = bf16_rne(v[2 * j] - bf16_f(h0));
      u16 h1 = bf16_rne(v[2 * j + 1]);
      u16 l1 = bf16_rne(v[2 * j + 1] - bf16_f(h1));
      Hh[j] = (u32)h0 | ((u32)h1 << 16);
      Ll[j] = (u32)l0 | ((u32)l1 << 16);
    }
    *(uint4*)(xh + i) = make_uint4(Hh[0], Hh[1], Hh[2], Hh[3]);
    *(uint4*)(xl + i) = make_uint4(Ll[0], Ll[1], Ll[2], Ll[3]);
  } else {
    int wb = bid - 2048;                    // [0,3072)
    int z = wb >> 10;
    int rem = wb & 1023;
    int by = (rem >> 5) * 32, bx = (rem & 31) * 32;
    const float* W = (z == 0) ? w0 : ((z == 1) ? w1 : w2);
    u16* th = ws + WT_HI_E + (size_t)z * (1u << 20);
    u16* tl = ws + WT_LO_E + (size_t)z * (1u << 20);
    __shared__ float tile[32][33];
    int tx = threadIdx.x & 31, ty = threadIdx.x >> 5;  // 32 x 8
#pragma unroll
    for (int i = 0; i < 4; i++) {
      int r = ty + i * 8;
      tile[r][tx] = W[(size_t)(by + r) * 1024 + bx + tx];
    }
    __syncthreads();
#pragma unroll
    for (int i = 0; i < 4; i++) {
      int r = ty + i * 8;
      float v = tile[tx][r];  // = W[by+tx][bx+r]
      int n = bx + r, k = by + tx;
      u16 h = bf16_rne(v);
      u16 l = bf16_rne(v - bf16_f(h));
      th[(size_t)n * 1024 + k] = h;
      tl[(size_t)n * 1024 + k] = l;
    }
  }
}

// ---------------- projections: Y = X @ W, compensated bf16 MFMA ----------------
// 64(M)x128(N) tiles, grid 1536 = 8 xcd x 8 m x 8 n x 3 z, XCD-affine M:
// each XCD owns a 512-row slice of X (2 MB hi+lo -> L2-resident) and loops n,z.
// z=0 -> Q*(0.125*log2e) (hi+lo), z=1 -> K (hi+lo, d-chunk swizzled),
// z=2 -> V (hi only, stored transposed, s-chunk swizzled per 64-key block).
__global__ __launch_bounds__(256, 4) void k_proj(u16* __restrict__ ws) {
  int id = blockIdx.x;
  int xcd = id & 7;
  int loc = id >> 3;            // 192 per XCD
  int m_loc = loc & 7;          // 8 M-blocks of 64 rows per XCD slice
  int rest = loc >> 3;          // 24 = 8 n x 3 z
  int n_blk = rest & 7, z = rest >> 3;
  int M0 = (xcd * 8 + m_loc) * 64;
  int N0 = n_blk * 128;

  const u16* Xh = ws + X_HI_E;
  const u16* Xl = ws + X_LO_E;
  const u16* Wh = ws + WT_HI_E + (size_t)z * (1u << 20);
  const u16* Wl = ws + WT_LO_E + (size_t)z * (1u << 20);
  u16* dsth = ws + ((z == 0) ? Q_HI_E : ((z == 1) ? K_HI_E : V_HI_E));
  u16* dstl = (z == 0) ? (ws + Q_LO_E) : ((z == 1) ? (ws + K_LO_E) : (u16*)0);

  __shared__ u16 sXh[2048], sXl[2048], sWh[4096], sWl[4096];  // 24 KB
  int tid = threadIdx.x, lane = tid & 63, w = tid >> 6;
  int quad = lane >> 4, l16 = lane & 15;
  int mb = (w & 1) * 32, nb = (w >> 1) * 64;

  const f32x4 z4 = {0.f, 0.f, 0.f, 0.f};
  f32x4 acc[2][4];
#pragma unroll
  for (int i = 0; i < 2; i++)
#pragma unroll
    for (int j = 0; j < 4; j++) acc[i][j] = z4;

  // staging: X row = tid>>2 (one chunk/thread); W rows via 2 chunks/thread
  int xrow = tid >> 2, xq8 = tid & 3;

  for (int kk = 0; kk < 1024; kk += 32) {
    __syncthreads();
    {
      size_t gx = (size_t)(M0 + xrow) * 1024 + kk + xq8 * 8;
      gload16(Xh + gx, &sXh[(size_t)(w * 16) * 32]);
      if (z != 2) gload16(Xl + gx, &sXl[(size_t)(w * 16) * 32]);
#pragma unroll
      for (int j = 0; j < 2; j++) {
        int c = tid + 256 * j;
        int row = c >> 2, q8 = c & 3;
        size_t gw = (size_t)(N0 + row) * 1024 + kk + q8 * 8;
        gload16(Wh + gw, &sWh[(size_t)(j * 64 + w * 16) * 32]);
        if (z != 2) gload16(Wl + gw, &sWl[(size_t)(j * 64 + w * 16) * 32]);
      }
    }
    __syncthreads();
    bf16x8 ah[2], bh[4];
#pragma unroll
    for (int i = 0; i < 2; i++)
      ah[i] = *(const bf16x8*)&sXh[(mb + i * 16 + l16) * 32 + quad * 8];
#pragma unroll
    for (int j = 0; j < 4; j++)
      bh[j] = *(const bf16x8*)&sWh[(nb + j * 16 + l16) * 32 + quad * 8];
    if (z != 2) {
      bf16x8 al[2], bl[4];
#pragma unroll
      for (int i = 0; i < 2; i++)
        al[i] = *(const bf16x8*)&sXl[(mb + i * 16 + l16) * 32 + quad * 8];
#pragma unroll
      for (int j = 0; j < 4; j++)
        bl[j] = *(const bf16x8*)&sWl[(nb + j * 16 + l16) * 32 + quad * 8];
#pragma unroll
      for (int i = 0; i < 2; i++)
#pragma unroll
        for (int j = 0; j < 4; j++) {
          f32x4 c0 = acc[i][j];
          c0 = __builtin_amdgcn_mfma_f32_16x16x32_bf16(ah[i], bh[j], c0, 0, 0, 0);
          c0 = __builtin_amdgcn_mfma_f32_16x16x32_bf16(ah[i], bl[j], c0, 0, 0, 0);
          c0 = __builtin_amdgcn_mfma_f32_16x16x32_bf16(al[i], bh[j], c0, 0, 0, 0);
          acc[i][j] = c0;
        }
    } else {
#pragma unroll
      for (int i = 0; i < 2; i++)
#pragma unroll
        for (int j = 0; j < 4; j++)
          acc[i][j] = __builtin_amdgcn_mfma_f32_16x16x32_bf16(ah[i], bh[j], acc[i][j], 0, 0, 0);
    }
  }

  if (z == 2) {
    // V^T store with s-chunk swizzle: chunk c -> c ^ (d&7) within 64-key block
#pragma unroll
    for (int i = 0; i < 2; i++)
#pragma unroll
      for (int j = 0; j < 4; j++) {
        int mg = M0 + mb + i * 16 + quad * 4;
        int ng = N0 + nb + j * 16 + l16;
        int b = mg >> 11, s = mg & 2047;
        int hh = ng >> 6, d = ng & 63;
        int cp = ((s >> 3) & 7) ^ (d & 7);
        int ssw = (s & ~63) | (cp << 3) | (s & 7);
        u16 p0 = bf16_rne(acc[i][j][0]);
        u16 p1 = bf16_rne(acc[i][j][1]);
        u16 p2 = bf16_rne(acc[i][j][2]);
        u16 p3 = bf16_rne(acc[i][j][3]);
        *(uint2*)&dsth[((size_t)(hh * 2 + b) * 64 + d) * 2048 + ssw] =
            make_uint2((u32)p0 | ((u32)p1 << 16), (u32)p2 | ((u32)p3 << 16));
      }
  } else {
    // Q scale: 1/sqrt(dh) * log2(e) -> scores land in log2 domain (exp2 softmax)
    float qscale = (z == 0) ? (0.125f * 1.4426950408889634f) : 1.0f;
#pragma unroll
    for (int i = 0; i < 2; i++)
#pragma unroll
      for (int j = 0; j < 4; j++)
#pragma unroll
        for (int r = 0; r < 4; r++) {
          int mg = M0 + mb + i * 16 + quad * 4 + r;
          int ng = N0 + nb + j * 16 + l16;
          int b = mg >> 11, s = mg & 2047;
          int hh = ng >> 6, d = ng & 63;
          int d2 = d;
          if (z == 1) d2 = ((((d >> 3) ^ (s & 7)) & 7) << 3) | (d & 7);  // K swizzle
          size_t idx = ((size_t)(hh * 2 + b) * 2048 + s) * 64 + d2;
          float y = acc[i][j][r] * qscale;
          u16 h = bf16_rne(y);
          dsth[idx] = h;
          dstl[idx] = bf16_rne(y - bf16_f(h));
        }
  }
}

// ---------------- flash attention: 32x32 MFMA, S^T in-register, dbuf ----------------
// grid 512 (= 2 blocks/CU), 4 waves/block, 32 queries/wave (BQ=128).
// Round-5 structure (measured 96 us) + exp2 softmax (Q pre-scaled by log2e).
__global__ __launch_bounds__(256, 2) void k_attn(u16* __restrict__ ws,
                                                 float* __restrict__ out) {
  const u16* Qh = ws + Q_HI_E;
  const u16* Ql = ws + Q_LO_E;
  const u16* Kh = ws + K_HI_E;
  const u16* Kl = ws + K_LO_E;
  const u16* Vt = ws + V_HI_E;

  __shared__ u16 sKh[2][64][64], sKl[2][64][64], sVt[2][64][64];  // 48 KB

  int id = blockIdx.x;
  int hb = id & 31, qb = id >> 5;  // id&7 = XCD: 4 hbs' K/V per XCD L2
  int tid = threadIdx.x, w = tid >> 6, lane = tid & 63;
  int l31 = lane & 31, h = lane >> 5;
  size_t base = (size_t)hb * (2048 * 64);
  int qw0 = qb * 128 + w * 32;

  int srow = lane >> 3, sch = lane & 7;  // staging: 8 rows x 128B per wave-instr

  auto stage = [&](int buf, int kt) {
#pragma unroll
    for (int b2 = 0; b2 < 2; b2++) {
      int rr = w * 16 + b2 * 8;
      size_t kg = base + (size_t)(kt + rr + srow) * 64 + sch * 8;
      gload16(Kh + kg, &sKh[buf][rr][0]);
      gload16(Kl + kg, &sKl[buf][rr][0]);
      size_t vg = base + (size_t)(rr + srow) * 2048 + kt + sch * 8;
      gload16(Vt + vg, &sVt[buf][rr][0]);
    }
  };

  stage(0, 0);

  // Q B-operand frags (n = query = l31, k-step ks: d = ks*16 + h*8), linear layout
  bf16x8 qh[4], ql[4];
#pragma unroll
  for (int ks = 0; ks < 4; ks++) {
    size_t off = base + (size_t)(qw0 + l31) * 64 + ks * 16 + h * 8;
    qh[ks] = *(const bf16x8*)(Qh + off);
    ql[ks] = *(const bf16x8*)(Ql + off);
  }

  f32x16 o[2];
#pragma unroll
  for (int i = 0; i < 16; i++) { o[0][i] = 0.f; o[1][i] = 0.f; }
  float mr = -1e30f, lr = 0.f;

  // A-operand read from a swizzled tile: row = mt*32 + l31, chunk = (ks*2+h)^(row&7)
  auto rdA = [&](const u16 t[64][64], int mt, int ks) -> bf16x8 {
    int ch = ((ks * 2 + h) ^ (l31 & 7)) * 8;
    return *(const bf16x8*)&t[mt * 32 + l31][ch];
  };

  for (int it = 0; it < 32; it++) {
    __syncthreads();
    if (it + 1 < 32) stage((it + 1) & 1, (it + 1) * 64);
    int buf = it & 1;

    // S^T = K·Q^T (compensated): lane holds query l31, its h-half of 64 keys
    f32x16 sc[2];
#pragma unroll
    for (int i = 0; i < 16; i++) { sc[0][i] = 0.f; sc[1][i] = 0.f; }
#pragma unroll
    for (int ks = 0; ks < 4; ks++)
#pragma unroll
      for (int mt = 0; mt < 2; mt++) {
        bf16x8 kh = rdA(sKh[buf], mt, ks);
        bf16x8 kl = rdA(sKl[buf], mt, ks);
        sc[mt] = __builtin_amdgcn_mfma_f32_32x32x16_bf16(kh, qh[ks], sc[mt], 0, 0, 0);
        sc[mt] = __builtin_amdgcn_mfma_f32_32x32x16_bf16(kh, ql[ks], sc[mt], 0, 0, 0);
        sc[mt] = __builtin_amdgcn_mfma_f32_32x32x16_bf16(kl, qh[ks], sc[mt], 0, 0, 0);
      }

    // online softmax (log2 domain): per-lane scalar stats, 1 shfl max + 1 shfl sum
    float mx = sc[0][0];
#pragma unroll
    for (int i = 0; i < 16; i++) {
      mx = fmaxf(mx, sc[0][i]);
      mx = fmaxf(mx, sc[1][i]);
    }
    mx = fmaxf(mx, __shfl_xor(mx, 32));
    float mnew = fmaxf(mr, mx);
    float alpha = __ocml_native_exp2_f32(mr - mnew);
    mr = mnew;
    float rs = 0.f;
    u32 pk[2][8];
#pragma unroll
    for (int t = 0; t < 2; t++)
#pragma unroll
      for (int i = 0; i < 8; i++) {
        float p0 = __ocml_native_exp2_f32(sc[t][2 * i] - mnew);
        float p1 = __ocml_native_exp2_f32(sc[t][2 * i + 1] - mnew);
        rs += p0 + p1;
        u32 a = __float_as_uint(p0) + 0x8000u;
        u32 b = __float_as_uint(p1) + 0x8000u;
        pk[t][i] = __builtin_amdgcn_perm(b, a, 0x07060302u);  // [hi16(a)|hi16(b)]
      }
    rs += __shfl_xor(rs, 32);
    lr = lr * alpha + rs;
#pragma unroll
    for (int i = 0; i < 16; i++) {
      o[0][i] *= alpha;
      o[1][i] *= alpha;
    }

    // O^T += V^T · P^T : B-frag (k=key, n=query) assembled from S^T regs via xor-32
#pragma unroll
    for (int ks = 0; ks < 4; ks++) {
      int t = ks >> 1, c = ks & 1;
      u32 b0 = pk[t][c * 4 + 0], b1 = pk[t][c * 4 + 1];
      u32 b2 = pk[t][c * 4 + 2], b3 = pk[t][c * 4 + 3];
      u32 rA = (u32)__shfl_xor((int)(h ? b0 : b2), 32);
      u32 rB = (u32)__shfl_xor((int)(h ? b1 : b3), 32);
      uint4 fb = h ? make_uint4(rA, rB, b2, b3) : make_uint4(b0, b1, rA, rB);
      bf16x8 pfrag = *(bf16x8*)&fb;
#pragma unroll
      for (int mt = 0; mt < 2; mt++) {
        bf16x8 vb = rdA(sVt[buf], mt, ks);
        o[mt] = __builtin_amdgcn_mfma_f32_32x32x16_bf16(vb, pfrag, o[mt], 0, 0, 0);
      }
    }
  }

  // epilogue: O^T C-layout col = query (per-lane lr), rows = d
  float inv = 1.f / lr;
  size_t grow = (size_t)hb * 2048 + qw0 + l31;
#pragma unroll
  for (int mt = 0; mt < 2; mt++)
#pragma unroll
    for (int g2 = 0; g2 < 4; g2++) {
      int d0 = mt * 32 + g2 * 8 + 4 * h;
      float4 v = make_float4(o[mt][g2 * 4 + 0] * inv, o[mt][g2 * 4 + 1] * inv,
                             o[mt][g2 * 4 + 2] * inv, o[mt][g2 * 4 + 3] * inv);
      *(float4*)(out + grow * 64 + d0) = v;
    }
}

extern "C" void kernel_launch(void* const* d_in, const int* in_sizes, int n_in,
                              void* d_out, int out_size, void* d_ws, size_t ws_size,
                              hipStream_t stream) {
  const float* X = (const float*)d_in[0];
  const float* Wq = (const float*)d_in[1];
  const float* Wk = (const float*)d_in[2];
  const float* Wv = (const float*)d_in[3];
  u16* ws = (u16*)d_ws;
  float* out = (float*)d_out;

  k_split<<<dim3(5120), dim3(256), 0, stream>>>(X, Wq, Wk, Wv, ws);
  k_proj<<<dim3(1536), dim3(256), 0, stream>>>(ws);
  k_attn<<<dim3(512), dim3(256), 0, stream>>>(ws, out);
}